// Round 7
// baseline (498.651 us; speedup 1.0000x reference)
//
#include <hip/hip_runtime.h>
#include <cstddef>
#include <cstdint>

// ---------------------------------------------------------------------------
// HGTConv, algebraically reduced:
//   softmax(scores).mean(-1) == 1/8 exactly  =>  attention path is dead code.
//   out = relu( mx @ (Wv@Wm@Wout)/8 + beta*((bv@Wm+bm)@Wout)/8 + bout + x )
//   with mx = segsum(x[src])/max(cnt,1), beta = (cnt>0).
//
// R8 (recompiled R9): R6 (sort) and R7 (index prefetch) both neutral ->
// gather is bound by HBM re-fetch of evicted rows (FETCH 271MB vs 154
// compulsory): the f32 gather pool (153.6MB) loses L3 residency to the
// 307MB epilogue streams. Fix: (1) gather from a bf16 copy xbf (76.8MB,
// L3-resident; built by grid-stride conv blocks fused into fuseE right
// before agg), (2) non-temporal loads/stores for all streaming traffic
// (conv x reads, epilogue x_res reads, out writes) so streams don't evict
// the pool. R9 fix: NT builtins need ext_vector_type, not HIP float4.
// ---------------------------------------------------------------------------

#define DD 256
#define SCAN_CHUNK 2048
#define NCONV 2048

typedef __attribute__((ext_vector_type(8))) short short8;
typedef __attribute__((ext_vector_type(4))) float floatx4;
typedef __attribute__((ext_vector_type(4))) short shortx4;

__device__ __forceinline__ short f2bf(float f) {
    union { float f; unsigned u; } c;
    c.f = f;
    unsigned r = c.u + 0x7fffu + ((c.u >> 16) & 1u);
    return (short)(r >> 16);
}
__device__ __forceinline__ float bflo(unsigned u) {
    union { unsigned u; float f; } c;
    c.u = u << 16;
    return c.f;
}
__device__ __forceinline__ float bfhi(unsigned u) {
    union { unsigned u; float f; } c;
    c.u = u & 0xffff0000u;
    return c.f;
}

// ---- fused launch A: weight GEMM stage 1 (T = Wv@Wm, x2) + both histograms
__global__ __launch_bounds__(256) void fuseA(const float* __restrict__ A0,
                                             const float* __restrict__ B0,
                                             float* __restrict__ C0,
                                             const float* __restrict__ A1,
                                             const float* __restrict__ B1,
                                             float* __restrict__ C1,
                                             const int* __restrict__ dst0,
                                             int* __restrict__ cnt0, int E0,
                                             const int* __restrict__ dst1,
                                             int* __restrict__ cnt1, int E1) {
    __shared__ float As[DD];
    const int bid = blockIdx.x;
    const int c = threadIdx.x;
    if (bid < 512) {
        const int which = bid >> 8;
        const int r = bid & 255;
        const float* A = which ? A1 : A0;
        const float* B = which ? B1 : B0;
        float* C = which ? C1 : C0;
        As[c] = A[r * DD + c];
        __syncthreads();
        float acc = 0.f;
#pragma unroll 8
        for (int k = 0; k < DD; ++k) acc += As[k] * B[k * DD + c];
        C[r * DD + c] = acc;
    } else {
        const int nb0 = (E0 + 255) >> 8;
        const int b = bid - 512;
        if (b < nb0) {
            const int i = b * 256 + c;
            if (i < E0) atomicAdd(&cnt0[dst0[i]], 1);
        } else {
            const int i = (b - nb0) * 256 + c;
            if (i < E1) atomicAdd(&cnt1[dst1[i]], 1);
        }
    }
}

// ---- fused launch B: Wf = T@Wout*0.125 -> swizzled bf16 (x2) + scan_chunk(x2)
// Bsw layout: Bsw[((k>>5)*16 + (n>>4))*64 + ((n&15)|(((k>>3)&3)<<4))][k&7]
__global__ __launch_bounds__(256) void fuseB(const float* __restrict__ A0,
                                             const float* __restrict__ B0,
                                             short* __restrict__ C0,
                                             const float* __restrict__ A1,
                                             const float* __restrict__ B1,
                                             short* __restrict__ C1,
                                             int* __restrict__ off_g,
                                             int* __restrict__ sums_g, int n_g,
                                             int* __restrict__ off_u,
                                             int* __restrict__ sums_u, int n_u) {
    __shared__ float As[DD];
    __shared__ int ls[256];
    const int bid = blockIdx.x;
    const int tid = threadIdx.x;
    if (bid < 512) {
        const int which = bid >> 8;
        const int r = bid & 255;  // k index of Wf
        const int c = tid;        // n index of Wf
        const float* A = which ? A1 : A0;
        const float* B = which ? B1 : B0;
        short* C = which ? C1 : C0;
        As[c] = A[r * DD + c];
        __syncthreads();
        float acc = 0.f;
#pragma unroll 8
        for (int k = 0; k < DD; ++k) acc += As[k] * B[k * DD + c];
        const int idx = ((((r >> 5) * 16 + (c >> 4)) * 64 +
                          ((c & 15) | (((r >> 3) & 3) << 4))) << 3) + (r & 7);
        C[idx] = f2bf(acc * 0.125f);
    } else {
        const int nch_g = (n_g + SCAN_CHUNK - 1) / SCAN_CHUNK;
        const int b = bid - 512;
        int* off;
        int* sums;
        int n, cb;
        if (b < nch_g) { off = off_g; sums = sums_g; n = n_g; cb = b; }
        else { off = off_u; sums = sums_u; n = n_u; cb = b - nch_g; }
        const int base = cb * SCAN_CHUNK + tid * 8;
        int v[8];
        int s = 0;
#pragma unroll
        for (int i = 0; i < 8; ++i) {
            const int idx = base + i;
            v[i] = (idx < n) ? off[idx] : 0;
            s += v[i];
        }
        ls[tid] = s;
        __syncthreads();
        for (int d = 1; d < 256; d <<= 1) {
            const int t = (tid >= d) ? ls[tid - d] : 0;
            __syncthreads();
            ls[tid] += t;
            __syncthreads();
        }
        int excl = tid ? ls[tid - 1] : 0;
        if (tid == 255) sums[cb] = ls[255];
#pragma unroll
        for (int i = 0; i < 8; ++i) {
            const int idx = base + i;
            if (idx < n) off[idx] = excl;
            excl += v[i];
        }
    }
}

// ---- fused launch C: bias fusion (2 blocks) + scan_sums (2 blocks)
__global__ __launch_bounds__(256) void fuseC(const float* __restrict__ bv0,
                                             const float* __restrict__ Wm0,
                                             const float* __restrict__ bm0,
                                             const float* __restrict__ Wout0,
                                             float* __restrict__ bb0,
                                             const float* __restrict__ bv1,
                                             const float* __restrict__ Wm1,
                                             const float* __restrict__ bm1,
                                             const float* __restrict__ Wout1,
                                             float* __restrict__ bb1,
                                             int* __restrict__ sums_g, int nch_g,
                                             int* __restrict__ sums_u, int nch_u) {
    __shared__ float t[DD];
    __shared__ int ls[256];
    const int tid = threadIdx.x;
    if (blockIdx.x < 2) {
        const int w = blockIdx.x;
        const float* bv = w ? bv1 : bv0;
        const float* Wm = w ? Wm1 : Wm0;
        const float* bm = w ? bm1 : bm0;
        const float* Wout = w ? Wout1 : Wout0;
        float* bb = w ? bb1 : bb0;
        float acc = bm[tid];
#pragma unroll 8
        for (int k = 0; k < DD; ++k) acc += bv[k] * Wm[k * DD + tid];
        t[tid] = acc;
        __syncthreads();
        float acc2 = 0.f;
#pragma unroll 8
        for (int k = 0; k < DD; ++k) acc2 += t[k] * Wout[k * DD + tid];
        bb[tid] = acc2 * 0.125f;
    } else {
        int* sums = (blockIdx.x == 2) ? sums_g : sums_u;
        const int nch = (blockIdx.x == 2) ? nch_g : nch_u;
        ls[tid] = (tid < nch) ? sums[tid] : 0;
        __syncthreads();
        for (int d = 1; d < 256; d <<= 1) {
            const int t2 = (tid >= d) ? ls[tid - d] : 0;
            __syncthreads();
            ls[tid] += t2;
            __syncthreads();
        }
        if (tid < nch) sums[tid] = tid ? ls[tid - 1] : 0;
    }
}

// ---- fused launch D: scan_add(x2) + cursor init
__global__ __launch_bounds__(256) void fuseD(int* __restrict__ off_g,
                                             const int* __restrict__ sums_g,
                                             int* __restrict__ cur_g, int n_g, int Eg,
                                             int* __restrict__ off_u,
                                             const int* __restrict__ sums_u,
                                             int* __restrict__ cur_u, int n_u, int Eu) {
    const int gidx = blockIdx.x * 256 + threadIdx.x;
    const int span_g = n_g + 1;
    if (gidx < span_g) {
        if (gidx < n_g) {
            const int v = off_g[gidx] + sums_g[gidx / SCAN_CHUNK];
            off_g[gidx] = v;
            cur_g[gidx] = v;
        } else {
            off_g[n_g] = Eg;
        }
    } else {
        const int idx = gidx - span_g;
        if (idx < n_u) {
            const int v = off_u[idx] + sums_u[idx / SCAN_CHUNK];
            off_u[idx] = v;
            cur_u[idx] = v;
        } else if (idx == n_u) {
            off_u[n_u] = Eu;
        }
    }
}

// ---- fused launch E: permute (x2) + xbf = bf16(x) conversion ---------------
// Conv blocks stream x (NT loads, no L3 pollution) into the 76.8MB bf16
// gather pool, immediately before agg so xbf is L3-hot.
__global__ __launch_bounds__(256) void fuseE(const int* __restrict__ src0,
                                             const int* __restrict__ dst0,
                                             int* __restrict__ cur0,
                                             int* __restrict__ perm0, int E0,
                                             const int* __restrict__ src1,
                                             const int* __restrict__ dst1,
                                             int* __restrict__ cur1,
                                             int* __restrict__ perm1, int E1,
                                             const float* __restrict__ xu,
                                             const float* __restrict__ xg,
                                             short* __restrict__ xbf,
                                             int n_user, int n_game) {
    const int nb0 = (E0 + 255) >> 8;
    const int nb1 = (E1 + 255) >> 8;
    const int nbperm = nb0 + nb1;
    const int b = blockIdx.x;
    const int tid = threadIdx.x;
    if (b < nb0) {
        const int i = b * 256 + tid;
        if (i < E0) {
            const int pos = atomicAdd(&cur0[dst0[i]], 1);
            perm0[pos] = src0[i];
        }
    } else if (b < nbperm) {
        const int i = (b - nb0) * 256 + tid;
        if (i < E1) {
            const int pos = atomicAdd(&cur1[dst1[i]], 1);
            perm1[pos] = src1[i];
        }
    } else {
        const size_t u4 = (size_t)n_user * 64;          // float4s in x_user
        const size_t tot4 = u4 + (size_t)n_game * 64;
        const size_t stride = (size_t)NCONV * 256;
        for (size_t i = (size_t)(b - nbperm) * 256 + tid; i < tot4; i += stride) {
            floatx4 v;
            if (i < u4)
                v = __builtin_nontemporal_load((const floatx4*)xu + i);
            else
                v = __builtin_nontemporal_load((const floatx4*)xg + (i - u4));
            shortx4 b4;
            b4.x = f2bf(v.x);
            b4.y = f2bf(v.y);
            b4.z = f2bf(v.z);
            b4.w = f2bf(v.w);
            *((shortx4*)xbf + i) = b4;
        }
    }
}

// ---- fused aggregate + bf16-MFMA GEMM + epilogue, BOTH passes in one grid --
// Block = 32 dst rows, 256 threads (4 waves, 8 rows/wave round-robin).
// Gather reads 512B bf16 rows from the L3-resident xbf pool; epilogue uses
// NT loads (x_res) and NT stores (out) to keep streams out of L3.
__global__ __launch_bounds__(256, 4) void agg_gemm6(
    const short* __restrict__ xbf,
    const float* __restrict__ x_user, const float* __restrict__ x_game,
    const int* __restrict__ perm_rev, const int* __restrict__ off_user,
    const short* __restrict__ Bsw_rev, const float* __restrict__ bb_rev,
    const float* __restrict__ bout_user,
    const int* __restrict__ perm_played, const int* __restrict__ off_game,
    const short* __restrict__ Bsw_played, const float* __restrict__ bb_played,
    const float* __restrict__ bout_game,
    float* __restrict__ outp, int n_user, int n_game, int nb_game) {
    __shared__ short As[32][264];
    __shared__ float bt[32];

    const int tid = threadIdx.x;
    const int wave = __builtin_amdgcn_readfirstlane(tid >> 6);
    const int lane = tid & 63;

    const short* xb_src;
    const float* x_res;
    const int* perm;
    const int* off;
    const short* Bsw;
    const float* bb;
    const float* bout;
    float* out;
    int M, r0;
    if ((int)blockIdx.x < nb_game) {
        // game pass first: deeper degrees -> longer blocks scheduled early
        xb_src = xbf;                                   // user rows
        x_res = x_game;
        perm = perm_played; off = off_game;
        Bsw = Bsw_played; bb = bb_played; bout = bout_game;
        out = outp + (size_t)n_user * DD;
        M = n_game;
        r0 = (int)blockIdx.x * 32;
    } else {
        xb_src = xbf + (size_t)n_user * DD;             // game rows
        x_res = x_user;
        perm = perm_rev; off = off_user;
        Bsw = Bsw_rev; bb = bb_rev; bout = bout_user;
        out = outp;
        M = n_user;
        r0 = ((int)blockIdx.x - nb_game) * 32;
    }

    // ---- phase 1: interleaved gather of 512B bf16 rows, 8 chains/wave ----
    int eb[8], deg[8];
    int s0[8], s1[8];
    float4 acc[8];
#pragma unroll
    for (int j = 0; j < 8; ++j) {
        const int r = r0 + wave * 8 + j;
        eb[j] = (r < M) ? off[r] : 0;
        const int e1 = (r < M) ? off[r + 1] : 0;
        deg[j] = e1 - eb[j];
        acc[j].x = 0.f; acc[j].y = 0.f; acc[j].z = 0.f; acc[j].w = 0.f;
        if (lane == 0) bt[wave * 8 + j] = (deg[j] > 0) ? 1.0f : 0.0f;
    }
#pragma unroll
    for (int j = 0; j < 8; ++j) {
        s0[j] = (deg[j] > 0) ? perm[eb[j]] : 0;
        s1[j] = (deg[j] > 1) ? perm[eb[j] + 1] : 0;
    }
    int mdeg = 0;
#pragma unroll
    for (int j = 0; j < 8; ++j) mdeg = max(mdeg, deg[j]);

    for (int t = 0; t < mdeg; ++t) {
        uint2 d[8];
        bool h[8];
#pragma unroll
        for (int j = 0; j < 8; ++j) {
            h[j] = t < deg[j];
            if (h[j])
                d[j] = *((const uint2*)(xb_src + (size_t)s0[j] * DD) + lane);
        }
        int s2[8];
#pragma unroll
        for (int j = 0; j < 8; ++j)
            s2[j] = (t + 2 < deg[j]) ? perm[eb[j] + t + 2] : 0;
#pragma unroll
        for (int j = 0; j < 8; ++j) {
            if (h[j]) {
                acc[j].x += bflo(d[j].x);
                acc[j].y += bfhi(d[j].x);
                acc[j].z += bflo(d[j].y);
                acc[j].w += bfhi(d[j].y);
            }
            s0[j] = s1[j];
            s1[j] = s2[j];
        }
    }
#pragma unroll
    for (int j = 0; j < 8; ++j) {
        const int lr = wave * 8 + j;
        const float inv = 1.0f / fmaxf((float)deg[j], 1.0f);
        short4 b4;
        b4.x = f2bf(acc[j].x * inv);
        b4.y = f2bf(acc[j].y * inv);
        b4.z = f2bf(acc[j].z * inv);
        b4.w = f2bf(acc[j].w * inv);
        *(short4*)&As[lr][lane * 4] = b4;
    }
    __syncthreads();

    // ---- phase 2: MFMA, 32 rows x 64 cols per wave ----
    const int quad = lane >> 4;
    const int l16 = lane & 15;
    floatx4 cacc[2][4];
#pragma unroll
    for (int rt = 0; rt < 2; ++rt)
#pragma unroll
        for (int ct = 0; ct < 4; ++ct) cacc[rt][ct] = (floatx4){0.f, 0.f, 0.f, 0.f};

    for (int kb8 = 0; kb8 < 8; ++kb8) {
        short8 af[2];
#pragma unroll
        for (int rt = 0; rt < 2; ++rt)
            af[rt] = *(const short8*)&As[rt * 16 + l16][kb8 * 32 + quad * 8];
        short8 bf[4];
        const short* bp = Bsw + (((size_t)(kb8 * 16 + wave * 4) * 64 + lane) << 3);
#pragma unroll
        for (int ct = 0; ct < 4; ++ct)
            bf[ct] = *(const short8*)(bp + (ct << 9));
#pragma unroll
        for (int rt = 0; rt < 2; ++rt)
#pragma unroll
            for (int ct = 0; ct < 4; ++ct)
                cacc[rt][ct] = __builtin_amdgcn_mfma_f32_16x16x32_bf16(
                    af[rt], bf[ct], cacc[rt][ct], 0, 0, 0);
    }

    // ---- epilogue (NT streams: no L3 allocation) ----
    float bbv[4], bov[4];
#pragma unroll
    for (int ct = 0; ct < 4; ++ct) {
        const int n = wave * 64 + ct * 16 + l16;
        bbv[ct] = bb[n];
        bov[ct] = bout[n];
    }
#pragma unroll
    for (int rt = 0; rt < 2; ++rt) {
#pragma unroll
        for (int j = 0; j < 4; ++j) {
            const int lr = rt * 16 + quad * 4 + j;
            const int r = r0 + lr;
            if (r < M) {
                const float btv = bt[lr];
                const float* xr = x_res + (size_t)r * DD;
                float* orow = out + (size_t)r * DD;
#pragma unroll
                for (int ct = 0; ct < 4; ++ct) {
                    const int n = wave * 64 + ct * 16 + l16;
                    const float xv = __builtin_nontemporal_load(xr + n);
                    const float o = cacc[rt][ct][j] + btv * bbv[ct] + bov[ct] + xv;
                    __builtin_nontemporal_store(fmaxf(o, 0.f), orow + n);
                }
            }
        }
    }
}

extern "C" void kernel_launch(void* const* d_in, const int* in_sizes, int n_in,
                              void* d_out, int out_size, void* d_ws, size_t ws_size,
                              hipStream_t stream) {
    const float* x_user = (const float*)d_in[0];
    const float* x_game = (const float*)d_in[1];
    const float* Wv_user = (const float*)d_in[6];
    const float* bv_user = (const float*)d_in[7];
    const float* Wout_user = (const float*)d_in[8];
    const float* bout_user = (const float*)d_in[9];
    const float* Wv_game = (const float*)d_in[14];
    const float* bv_game = (const float*)d_in[15];
    const float* Wout_game = (const float*)d_in[16];
    const float* bout_game = (const float*)d_in[17];
    const float* Wm_played = (const float*)d_in[20];
    const float* bm_played = (const float*)d_in[21];
    const float* Wm_rev = (const float*)d_in[24];
    const float* bm_rev = (const float*)d_in[25];
    const int* ei_played_src = (const int*)d_in[26];
    const int* ei_played_dst = (const int*)d_in[27];
    const int* ei_rev_src = (const int*)d_in[28];
    const int* ei_rev_dst = (const int*)d_in[29];

    const int n_user = in_sizes[0] / DD;
    const int n_game = in_sizes[1] / DD;
    const int e_played = in_sizes[26];
    const int e_rev = in_sizes[28];

    float* out = (float*)d_out;

    // ---- workspace layout ----
    float* fws = (float*)d_ws;
    float* T0 = fws;                       // 64K f32
    float* T1 = T0 + DD * DD;              // 64K f32
    float* bb_played = T1 + DD * DD;       // 256
    float* bb_rev = bb_played + DD;        // 256
    short* Bsw_played = (short*)(bb_rev + DD);   // 64K bf16
    short* Bsw_rev = Bsw_played + DD * DD;       // 64K bf16
    int* iws = (int*)(Bsw_rev + DD * DD);
    int* off_game = iws;                      // n_game+1
    int* off_user = off_game + (n_game + 1);  // n_user+1
    int* cursor_game = off_user + (n_user + 1);
    int* cursor_user = cursor_game + n_game;
    int* sums_game = cursor_user + n_user;    // 256
    int* sums_user = sums_game + 256;         // 256
    int* perm_played = sums_user + 256;       // E
    int* perm_rev = perm_played + e_played;   // E
    uintptr_t xaddr = (uintptr_t)(perm_rev + e_rev);
    xaddr = (xaddr + 255) & ~(uintptr_t)255;
    short* xbf = (short*)xaddr;               // (n_user+n_game) x 256 bf16
    (void)ws_size; (void)n_in; (void)out_size;

    // ---- zero histograms (off_game & off_user contiguous) ----
    hipMemsetAsync(off_game, 0, (size_t)(n_game + n_user + 2) * sizeof(int), stream);

    const int nbh_p = (e_played + 255) / 256;
    const int nbh_r = (e_rev + 255) / 256;
    const int nch_g = (n_game + SCAN_CHUNK - 1) / SCAN_CHUNK;
    const int nch_u = (n_user + SCAN_CHUNK - 1) / SCAN_CHUNK;

    // A: weight GEMM stage1 + histograms
    fuseA<<<512 + nbh_p + nbh_r, 256, 0, stream>>>(
        Wv_user, Wm_played, T0, Wv_game, Wm_rev, T1,
        ei_played_dst, off_game, e_played, ei_rev_dst, off_user, e_rev);
    // B: weight GEMM stage2 (swizzled bf16) + chunk scans
    fuseB<<<512 + nch_g + nch_u, 256, 0, stream>>>(
        T0, Wout_game, Bsw_played, T1, Wout_user, Bsw_rev,
        off_game, sums_game, n_game, off_user, sums_user, n_user);
    // C: bias fusion + chunk-sum scans
    fuseC<<<4, 256, 0, stream>>>(
        bv_user, Wm_played, bm_played, Wout_game, bb_played,
        bv_game, Wm_rev, bm_rev, Wout_user, bb_rev,
        sums_game, nch_g, sums_user, nch_u);
    // D: scan finalize + cursor init
    const int ntot = (n_game + 1) + (n_user + 1);
    fuseD<<<(ntot + 255) / 256, 256, 0, stream>>>(
        off_game, sums_game, cursor_game, n_game, e_played,
        off_user, sums_user, cursor_user, n_user, e_rev);
    // E: permute both edge lists + xbf conversion (L3-hot for agg)
    fuseE<<<nbh_p + nbh_r + NCONV, 256, 0, stream>>>(
        ei_played_src, ei_played_dst, cursor_game, perm_played, e_played,
        ei_rev_src, ei_rev_dst, cursor_user, perm_rev, e_rev,
        x_user, x_game, xbf, n_user, n_game);

    // ---- fused aggregate + GEMM + epilogue, both passes in one grid ----
    const int nb_game = (n_game + 31) / 32;
    const int nb_user = (n_user + 31) / 32;
    agg_gemm6<<<nb_game + nb_user, 256, 0, stream>>>(
        xbf, x_user, x_game, perm_rev, off_user, Bsw_rev, bb_rev, bout_user,
        perm_played, off_game, Bsw_played, bb_played, bout_game,
        out, n_user, n_game, nb_game);
}

// Round 9
// 480.759 us; speedup vs baseline: 1.0372x; 1.0372x over previous
//
#include <hip/hip_runtime.h>
#include <cstddef>
#include <cstdint>

// ---------------------------------------------------------------------------
// HGTConv, algebraically reduced:
//   softmax(scores).mean(-1) == 1/8 exactly  =>  attention path is dead code.
//   out = relu( mx @ (Wv@Wm@Wout)/8 + beta*((bv@Wm+bm)@Wout)/8 + bout + x )
//   with mx = segsum(x[src])/max(cnt,1), beta = (cnt>0).
//
// R10 (resubmit after infra failure): R8/9 validated the bf16-gather-pool +
// NT-stream theory (FETCH 271->171, agg 148->127) but serialized the
// conversion in fuseE (+40us). This round:
//   - conv + bias-fuse move into fuseA (overlap under the whole CSR chain)
//   - fuseC deleted (fuseD recomputes the <=49-element chunk-sum scan in LDS)
//   - agg gather double-buffered: issue round t+1's 8 row-loads before
//     accumulating round t -> 16 rows in flight per wave (2x MLP)
// ---------------------------------------------------------------------------

#define DD 256
#define SCAN_CHUNK 2048
#define NCONV 2048

typedef __attribute__((ext_vector_type(8))) short short8;
typedef __attribute__((ext_vector_type(4))) float floatx4;
typedef __attribute__((ext_vector_type(4))) short shortx4;

__device__ __forceinline__ short f2bf(float f) {
    union { float f; unsigned u; } c;
    c.f = f;
    unsigned r = c.u + 0x7fffu + ((c.u >> 16) & 1u);
    return (short)(r >> 16);
}
__device__ __forceinline__ float bflo(unsigned u) {
    union { unsigned u; float f; } c;
    c.u = u << 16;
    return c.f;
}
__device__ __forceinline__ float bfhi(unsigned u) {
    union { unsigned u; float f; } c;
    c.u = u & 0xffff0000u;
    return c.f;
}

// ---- fused launch A: gemm1 (T=Wv@Wm x2) + bias fuse (x2) + histograms + conv
__global__ __launch_bounds__(256) void fuseA(
    const float* __restrict__ A0, const float* __restrict__ B0, float* __restrict__ C0,
    const float* __restrict__ A1, const float* __restrict__ B1, float* __restrict__ C1,
    const float* __restrict__ bv0, const float* __restrict__ Wm0,
    const float* __restrict__ bm0, const float* __restrict__ Wout0,
    float* __restrict__ bb0,
    const float* __restrict__ bv1, const float* __restrict__ Wm1,
    const float* __restrict__ bm1, const float* __restrict__ Wout1,
    float* __restrict__ bb1,
    const int* __restrict__ dst0, int* __restrict__ cnt0, int E0,
    const int* __restrict__ dst1, int* __restrict__ cnt1, int E1,
    const float* __restrict__ xu, const float* __restrict__ xg,
    short* __restrict__ xbf, int n_user, int n_game) {
    __shared__ float As[DD];
    const int bid = blockIdx.x;
    const int c = threadIdx.x;
    const int nb0 = (E0 + 255) >> 8;
    const int nb1 = (E1 + 255) >> 8;
    if (bid < 512) {
        const int which = bid >> 8;
        const int r = bid & 255;
        const float* A = which ? A1 : A0;
        const float* B = which ? B1 : B0;
        float* C = which ? C1 : C0;
        As[c] = A[r * DD + c];
        __syncthreads();
        float acc = 0.f;
#pragma unroll 8
        for (int k = 0; k < DD; ++k) acc += As[k] * B[k * DD + c];
        C[r * DD + c] = acc;
    } else if (bid < 514) {
        const int w = bid - 512;
        const float* bv = w ? bv1 : bv0;
        const float* Wm = w ? Wm1 : Wm0;
        const float* bm = w ? bm1 : bm0;
        const float* Wout = w ? Wout1 : Wout0;
        float* bb = w ? bb1 : bb0;
        float acc = bm[c];
#pragma unroll 8
        for (int k = 0; k < DD; ++k) acc += bv[k] * Wm[k * DD + c];
        As[c] = acc;
        __syncthreads();
        float acc2 = 0.f;
#pragma unroll 8
        for (int k = 0; k < DD; ++k) acc2 += As[k] * Wout[k * DD + c];
        bb[c] = acc2 * 0.125f;
    } else if (bid < 514 + nb0 + nb1) {
        const int b = bid - 514;
        if (b < nb0) {
            const int i = b * 256 + c;
            if (i < E0) atomicAdd(&cnt0[dst0[i]], 1);
        } else {
            const int i = (b - nb0) * 256 + c;
            if (i < E1) atomicAdd(&cnt1[dst1[i]], 1);
        }
    } else {
        // xbf = bf16(x): NT stream reads, writes allocate in L3 (gather pool)
        const size_t u4 = (size_t)n_user * 64;
        const size_t tot4 = u4 + (size_t)n_game * 64;
        const size_t stride = (size_t)NCONV * 256;
        for (size_t i = (size_t)(bid - 514 - nb0 - nb1) * 256 + c; i < tot4;
             i += stride) {
            floatx4 v;
            if (i < u4)
                v = __builtin_nontemporal_load((const floatx4*)xu + i);
            else
                v = __builtin_nontemporal_load((const floatx4*)xg + (i - u4));
            shortx4 b4;
            b4.x = f2bf(v.x);
            b4.y = f2bf(v.y);
            b4.z = f2bf(v.z);
            b4.w = f2bf(v.w);
            *((shortx4*)xbf + i) = b4;
        }
    }
}

// ---- fused launch B: Wf = T@Wout*0.125 -> swizzled bf16 (x2) + scan_chunk(x2)
// Bsw layout: Bsw[((k>>5)*16 + (n>>4))*64 + ((n&15)|(((k>>3)&3)<<4))][k&7]
__global__ __launch_bounds__(256) void fuseB(const float* __restrict__ A0,
                                             const float* __restrict__ B0,
                                             short* __restrict__ C0,
                                             const float* __restrict__ A1,
                                             const float* __restrict__ B1,
                                             short* __restrict__ C1,
                                             int* __restrict__ off_g,
                                             int* __restrict__ sums_g, int n_g,
                                             int* __restrict__ off_u,
                                             int* __restrict__ sums_u, int n_u) {
    __shared__ float As[DD];
    __shared__ int ls[256];
    const int bid = blockIdx.x;
    const int tid = threadIdx.x;
    if (bid < 512) {
        const int which = bid >> 8;
        const int r = bid & 255;  // k index of Wf
        const int c = tid;        // n index of Wf
        const float* A = which ? A1 : A0;
        const float* B = which ? B1 : B0;
        short* C = which ? C1 : C0;
        As[c] = A[r * DD + c];
        __syncthreads();
        float acc = 0.f;
#pragma unroll 8
        for (int k = 0; k < DD; ++k) acc += As[k] * B[k * DD + c];
        const int idx = ((((r >> 5) * 16 + (c >> 4)) * 64 +
                          ((c & 15) | (((r >> 3) & 3) << 4))) << 3) + (r & 7);
        C[idx] = f2bf(acc * 0.125f);
    } else {
        const int nch_g = (n_g + SCAN_CHUNK - 1) / SCAN_CHUNK;
        const int b = bid - 512;
        int* off;
        int* sums;
        int n, cb;
        if (b < nch_g) { off = off_g; sums = sums_g; n = n_g; cb = b; }
        else { off = off_u; sums = sums_u; n = n_u; cb = b - nch_g; }
        const int base = cb * SCAN_CHUNK + tid * 8;
        int v[8];
        int s = 0;
#pragma unroll
        for (int i = 0; i < 8; ++i) {
            const int idx = base + i;
            v[i] = (idx < n) ? off[idx] : 0;
            s += v[i];
        }
        ls[tid] = s;
        __syncthreads();
        for (int d = 1; d < 256; d <<= 1) {
            const int t = (tid >= d) ? ls[tid - d] : 0;
            __syncthreads();
            ls[tid] += t;
            __syncthreads();
        }
        int excl = tid ? ls[tid - 1] : 0;
        if (tid == 255) sums[cb] = ls[255];
#pragma unroll
        for (int i = 0; i < 8; ++i) {
            const int idx = base + i;
            if (idx < n) off[idx] = excl;
            excl += v[i];
        }
    }
}

// ---- fused launch D: scan_add(x2) + cursor init; per-block redundant
//      LDS scan of the (<=49 + <=25) raw chunk sums replaces fuseC.
__global__ __launch_bounds__(256) void fuseD(int* __restrict__ off_g,
                                             const int* __restrict__ sums_g,
                                             int* __restrict__ cur_g, int n_g, int Eg,
                                             int* __restrict__ off_u,
                                             const int* __restrict__ sums_u,
                                             int* __restrict__ cur_u, int n_u, int Eu,
                                             int nch_g, int nch_u) {
    __shared__ int ls[128];
    const int tid = threadIdx.x;
    if (tid < 128) {
        int v = 0;
        if (tid < 64) {
            if (tid < nch_g) v = sums_g[tid];
        } else {
            if (tid - 64 < nch_u) v = sums_u[tid - 64];
        }
        ls[tid] = v;
    }
    __syncthreads();
    // inclusive Hillis-Steele scan, restarting at slot 64
    for (int d = 1; d < 64; d <<= 1) {
        int t2 = 0;
        if (tid < 128 && (tid & 63) >= d) t2 = ls[tid - d];
        __syncthreads();
        if (tid < 128) ls[tid] += t2;
        __syncthreads();
    }
    const int gidx = blockIdx.x * 256 + tid;
    const int span_g = n_g + 1;
    if (gidx < span_g) {
        if (gidx < n_g) {
            const int cg = gidx / SCAN_CHUNK;
            const int v = off_g[gidx] + (cg ? ls[cg - 1] : 0);
            off_g[gidx] = v;
            cur_g[gidx] = v;
        } else {
            off_g[n_g] = Eg;
        }
    } else {
        const int idx = gidx - span_g;
        if (idx < n_u) {
            const int cu = idx / SCAN_CHUNK;
            const int v = off_u[idx] + (cu ? ls[64 + cu - 1] : 0);
            off_u[idx] = v;
            cur_u[idx] = v;
        } else if (idx == n_u) {
            off_u[n_u] = Eu;
        }
    }
}

// ---- fused launch E: permute (x2)
__global__ __launch_bounds__(256) void fuseE(const int* __restrict__ src0,
                                             const int* __restrict__ dst0,
                                             int* __restrict__ cur0,
                                             int* __restrict__ perm0, int E0,
                                             const int* __restrict__ src1,
                                             const int* __restrict__ dst1,
                                             int* __restrict__ cur1,
                                             int* __restrict__ perm1, int E1) {
    const int nb0 = (E0 + 255) >> 8;
    const int b = blockIdx.x;
    const int tid = threadIdx.x;
    if (b < nb0) {
        const int i = b * 256 + tid;
        if (i < E0) {
            const int pos = atomicAdd(&cur0[dst0[i]], 1);
            perm0[pos] = src0[i];
        }
    } else {
        const int i = (b - nb0) * 256 + tid;
        if (i < E1) {
            const int pos = atomicAdd(&cur1[dst1[i]], 1);
            perm1[pos] = src1[i];
        }
    }
}

// ---- fused aggregate + bf16-MFMA GEMM + epilogue, BOTH passes in one grid --
// Block = 32 dst rows, 256 threads (4 waves, 8 rows/wave round-robin).
// Gather: 512B bf16 rows from the L3-resident xbf pool, DOUBLE-BUFFERED:
// round t+1's 8 row-loads issue before round t's accumulate -> 16 rows in
// flight per wave. Epilogue: NT loads (x_res) and NT stores (out).
__global__ __launch_bounds__(256, 4) void agg_gemm7(
    const short* __restrict__ xbf,
    const float* __restrict__ x_user, const float* __restrict__ x_game,
    const int* __restrict__ perm_rev, const int* __restrict__ off_user,
    const short* __restrict__ Bsw_rev, const float* __restrict__ bb_rev,
    const float* __restrict__ bout_user,
    const int* __restrict__ perm_played, const int* __restrict__ off_game,
    const short* __restrict__ Bsw_played, const float* __restrict__ bb_played,
    const float* __restrict__ bout_game,
    float* __restrict__ outp, int n_user, int n_game, int nb_game) {
    __shared__ short As[32][264];
    __shared__ float bt[32];

    const int tid = threadIdx.x;
    const int wave = __builtin_amdgcn_readfirstlane(tid >> 6);
    const int lane = tid & 63;

    const short* xb_src;
    const float* x_res;
    const int* perm;
    const int* off;
    const short* Bsw;
    const float* bb;
    const float* bout;
    float* out;
    int M, r0;
    if ((int)blockIdx.x < nb_game) {
        xb_src = xbf;                                   // user rows
        x_res = x_game;
        perm = perm_played; off = off_game;
        Bsw = Bsw_played; bb = bb_played; bout = bout_game;
        out = outp + (size_t)n_user * DD;
        M = n_game;
        r0 = (int)blockIdx.x * 32;
    } else {
        xb_src = xbf + (size_t)n_user * DD;             // game rows
        x_res = x_user;
        perm = perm_rev; off = off_user;
        Bsw = Bsw_rev; bb = bb_rev; bout = bout_user;
        out = outp;
        M = n_user;
        r0 = ((int)blockIdx.x - nb_game) * 32;
    }

    // ---- phase 1: double-buffered interleaved gather, 8 rows/wave ----
    int eb[8], deg[8];
    int sB[8];
    uint2 dA[8], dB[8];
    float4 acc[8];
#pragma unroll
    for (int j = 0; j < 8; ++j) {
        const int r = r0 + wave * 8 + j;
        eb[j] = (r < M) ? off[r] : 0;
        const int e1 = (r < M) ? off[r + 1] : 0;
        deg[j] = e1 - eb[j];
        acc[j].x = 0.f; acc[j].y = 0.f; acc[j].z = 0.f; acc[j].w = 0.f;
        if (lane == 0) bt[wave * 8 + j] = (deg[j] > 0) ? 1.0f : 0.0f;
    }
    // prologue: issue round 0, prefetch index of round 1
#pragma unroll
    for (int j = 0; j < 8; ++j) {
        if (deg[j] > 0) {
            const int sA = perm[eb[j]];
            dA[j] = *((const uint2*)(xb_src + (size_t)sA * DD) + lane);
        }
    }
#pragma unroll
    for (int j = 0; j < 8; ++j) sB[j] = (deg[j] > 1) ? perm[eb[j] + 1] : 0;

    int mdeg = 0;
#pragma unroll
    for (int j = 0; j < 8; ++j) mdeg = max(mdeg, deg[j]);

    for (int t = 0; t < mdeg; t += 2) {
        // issue round t+1 (dB)
#pragma unroll
        for (int j = 0; j < 8; ++j)
            if (t + 1 < deg[j])
                dB[j] = *((const uint2*)(xb_src + (size_t)sB[j] * DD) + lane);
        // prefetch index for round t+2
        int sC[8];
#pragma unroll
        for (int j = 0; j < 8; ++j)
            sC[j] = (t + 2 < deg[j]) ? perm[eb[j] + t + 2] : 0;
        // accumulate round t (dA)
#pragma unroll
        for (int j = 0; j < 8; ++j) {
            if (t < deg[j]) {
                acc[j].x += bflo(dA[j].x);
                acc[j].y += bfhi(dA[j].x);
                acc[j].z += bflo(dA[j].y);
                acc[j].w += bfhi(dA[j].y);
            }
        }
        // issue round t+2 (dA)
#pragma unroll
        for (int j = 0; j < 8; ++j)
            if (t + 2 < deg[j])
                dA[j] = *((const uint2*)(xb_src + (size_t)sC[j] * DD) + lane);
        // prefetch index for round t+3
        int sD[8];
#pragma unroll
        for (int j = 0; j < 8; ++j)
            sD[j] = (t + 3 < deg[j]) ? perm[eb[j] + t + 3] : 0;
        // accumulate round t+1 (dB), rotate index pipeline
#pragma unroll
        for (int j = 0; j < 8; ++j) {
            if (t + 1 < deg[j]) {
                acc[j].x += bflo(dB[j].x);
                acc[j].y += bfhi(dB[j].x);
                acc[j].z += bflo(dB[j].y);
                acc[j].w += bfhi(dB[j].y);
            }
            sB[j] = sD[j];
        }
    }
#pragma unroll
    for (int j = 0; j < 8; ++j) {
        const int lr = wave * 8 + j;
        const float inv = 1.0f / fmaxf((float)deg[j], 1.0f);
        short4 b4;
        b4.x = f2bf(acc[j].x * inv);
        b4.y = f2bf(acc[j].y * inv);
        b4.z = f2bf(acc[j].z * inv);
        b4.w = f2bf(acc[j].w * inv);
        *(short4*)&As[lr][lane * 4] = b4;
    }
    __syncthreads();

    // ---- phase 2: MFMA, 32 rows x 64 cols per wave ----
    const int quad = lane >> 4;
    const int l16 = lane & 15;
    floatx4 cacc[2][4];
#pragma unroll
    for (int rt = 0; rt < 2; ++rt)
#pragma unroll
        for (int ct = 0; ct < 4; ++ct) cacc[rt][ct] = (floatx4){0.f, 0.f, 0.f, 0.f};

    for (int kb8 = 0; kb8 < 8; ++kb8) {
        short8 af[2];
#pragma unroll
        for (int rt = 0; rt < 2; ++rt)
            af[rt] = *(const short8*)&As[rt * 16 + l16][kb8 * 32 + quad * 8];
        short8 bf[4];
        const short* bp = Bsw + (((size_t)(kb8 * 16 + wave * 4) * 64 + lane) << 3);
#pragma unroll
        for (int ct = 0; ct < 4; ++ct)
            bf[ct] = *(const short8*)(bp + (ct << 9));
#pragma unroll
        for (int rt = 0; rt < 2; ++rt)
#pragma unroll
            for (int ct = 0; ct < 4; ++ct)
                cacc[rt][ct] = __builtin_amdgcn_mfma_f32_16x16x32_bf16(
                    af[rt], bf[ct], cacc[rt][ct], 0, 0, 0);
    }

    // ---- epilogue (NT streams: no L3 allocation) ----
    float bbv[4], bov[4];
#pragma unroll
    for (int ct = 0; ct < 4; ++ct) {
        const int n = wave * 64 + ct * 16 + l16;
        bbv[ct] = bb[n];
        bov[ct] = bout[n];
    }
#pragma unroll
    for (int rt = 0; rt < 2; ++rt) {
#pragma unroll
        for (int j = 0; j < 4; ++j) {
            const int lr = rt * 16 + quad * 4 + j;
            const int r = r0 + lr;
            if (r < M) {
                const float btv = bt[lr];
                const float* xr = x_res + (size_t)r * DD;
                float* orow = out + (size_t)r * DD;
#pragma unroll
                for (int ct = 0; ct < 4; ++ct) {
                    const int n = wave * 64 + ct * 16 + l16;
                    const float xv = __builtin_nontemporal_load(xr + n);
                    const float o = cacc[rt][ct][j] + btv * bbv[ct] + bov[ct] + xv;
                    __builtin_nontemporal_store(fmaxf(o, 0.f), orow + n);
                }
            }
        }
    }
}

extern "C" void kernel_launch(void* const* d_in, const int* in_sizes, int n_in,
                              void* d_out, int out_size, void* d_ws, size_t ws_size,
                              hipStream_t stream) {
    const float* x_user = (const float*)d_in[0];
    const float* x_game = (const float*)d_in[1];
    const float* Wv_user = (const float*)d_in[6];
    const float* bv_user = (const float*)d_in[7];
    const float* Wout_user = (const float*)d_in[8];
    const float* bout_user = (const float*)d_in[9];
    const float* Wv_game = (const float*)d_in[14];
    const float* bv_game = (const float*)d_in[15];
    const float* Wout_game = (const float*)d_in[16];
    const float* bout_game = (const float*)d_in[17];
    const float* Wm_played = (const float*)d_in[20];
    const float* bm_played = (const float*)d_in[21];
    const float* Wm_rev = (const float*)d_in[24];
    const float* bm_rev = (const float*)d_in[25];
    const int* ei_played_src = (const int*)d_in[26];
    const int* ei_played_dst = (const int*)d_in[27];
    const int* ei_rev_src = (const int*)d_in[28];
    const int* ei_rev_dst = (const int*)d_in[29];

    const int n_user = in_sizes[0] / DD;
    const int n_game = in_sizes[1] / DD;
    const int e_played = in_sizes[26];
    const int e_rev = in_sizes[28];

    float* out = (float*)d_out;

    // ---- workspace layout ----
    float* fws = (float*)d_ws;
    float* T0 = fws;                       // 64K f32
    float* T1 = T0 + DD * DD;              // 64K f32
    float* bb_played = T1 + DD * DD;       // 256
    float* bb_rev = bb_played + DD;        // 256
    short* Bsw_played = (short*)(bb_rev + DD);   // 64K bf16
    short* Bsw_rev = Bsw_played + DD * DD;       // 64K bf16
    int* iws = (int*)(Bsw_rev + DD * DD);
    int* off_game = iws;                      // n_game+1
    int* off_user = off_game + (n_game + 1);  // n_user+1
    int* cursor_game = off_user + (n_user + 1);
    int* cursor_user = cursor_game + n_game;
    int* sums_game = cursor_user + n_user;    // 256
    int* sums_user = sums_game + 256;         // 256
    int* perm_played = sums_user + 256;       // E
    int* perm_rev = perm_played + e_played;   // E
    uintptr_t xaddr = (uintptr_t)(perm_rev + e_rev);
    xaddr = (xaddr + 255) & ~(uintptr_t)255;
    short* xbf = (short*)xaddr;               // (n_user+n_game) x 256 bf16
    (void)ws_size; (void)n_in; (void)out_size;

    // ---- zero histograms (off_game & off_user contiguous) ----
    hipMemsetAsync(off_game, 0, (size_t)(n_game + n_user + 2) * sizeof(int), stream);

    const int nbh_p = (e_played + 255) / 256;
    const int nbh_r = (e_rev + 255) / 256;
    const int nch_g = (n_game + SCAN_CHUNK - 1) / SCAN_CHUNK;
    const int nch_u = (n_user + SCAN_CHUNK - 1) / SCAN_CHUNK;

    // A: gemm1 + bias fuse + histograms + xbf conversion (overlapped)
    fuseA<<<512 + 2 + nbh_p + nbh_r + NCONV, 256, 0, stream>>>(
        Wv_user, Wm_played, T0, Wv_game, Wm_rev, T1,
        bv_user, Wm_played, bm_played, Wout_game, bb_played,
        bv_game, Wm_rev, bm_rev, Wout_user, bb_rev,
        ei_played_dst, off_game, e_played, ei_rev_dst, off_user, e_rev,
        x_user, x_game, xbf, n_user, n_game);
    // B: gemm2 (swizzled bf16) + chunk scans
    fuseB<<<512 + nch_g + nch_u, 256, 0, stream>>>(
        T0, Wout_game, Bsw_played, T1, Wout_user, Bsw_rev,
        off_game, sums_game, n_game, off_user, sums_user, n_user);
    // D: scan finalize (per-block redundant top-scan) + cursor init
    const int ntot = (n_game + 1) + (n_user + 1);
    fuseD<<<(ntot + 255) / 256, 256, 0, stream>>>(
        off_game, sums_game, cursor_game, n_game, e_played,
        off_user, sums_user, cursor_user, n_user, e_rev, nch_g, nch_u);
    // E: permute both edge lists
    fuseE<<<nbh_p + nbh_r, 256, 0, stream>>>(
        ei_played_src, ei_played_dst, cursor_game, perm_played, e_played,
        ei_rev_src, ei_rev_dst, cursor_user, perm_rev, e_rev);

    // ---- fused aggregate + GEMM + epilogue, both passes in one grid ----
    const int nb_game = (n_game + 31) / 32;
    const int nb_user = (n_user + 31) / 32;
    agg_gemm7<<<nb_game + nb_user, 256, 0, stream>>>(
        xbf, x_user, x_game, perm_rev, off_user, Bsw_rev, bb_rev, bout_user,
        perm_played, off_game, Bsw_played, bb_played, bout_game,
        out, n_user, n_game, nb_game);
}